// Round 3
// baseline (112.759 us; speedup 1.0000x reference)
//
#include <hip/hip_runtime.h>

// out[s,i] = Re( sum_j U[i,j] x[s,j] )  — harness coerces the complex64
// reference to float32 (real part), out_size = 2048*1024 floats.
//
// U = M1·M2·...·M100 where each program-order op right-multiplies the column
// index (U3 embeds G^T, CNOT embeds its own permutation P). So
// U·x = M1(M2(...(M100 x))): apply ops to x in REVERSE program order.
// For l=4..0: [CNOT q=9..0, composed into one index permutation] then
// [U3 with h = G^T, q=9..0]. Qubit q <-> bit (9-q) of the flat index.

#define NQ 10
#define NL 5
#define NST 1024
#define NTHREADS 512

__global__ __launch_bounds__(NTHREADS) void qc_apply(
    const float* __restrict__ x, const float* __restrict__ w,
    float* __restrict__ out, int out_size) {
  __shared__ float sre[NST];
  __shared__ float sim[NST];
  __shared__ float g[NL * NQ * 8];  // transposed U3 gates, 4 complex entries

  const int s = blockIdx.x;   // state index (b*16+c)
  const int t = threadIdx.x;  // 0..511

  // Load real input state; imag = 0.
  const float* xs = x + (size_t)s * NST;
  sre[t] = xs[t];
  sre[t + NTHREADS] = xs[t + NTHREADS];
  sim[t] = 0.0f;
  sim[t + NTHREADS] = 0.0f;

  // Build all 50 TRANSPOSED gate matrices (h = g^T: h01=g10, h10=g01).
  if (t < NL * NQ) {
    const float th = w[t * 3 + 0];
    const float ph = w[t * 3 + 1];
    const float lm = w[t * 3 + 2];
    const float ch = cosf(0.5f * th);
    const float sh = sinf(0.5f * th);
    const float cl = cosf(lm),       sl = sinf(lm);
    const float cp = cosf(ph),       sp = sinf(ph);
    const float cpl = cosf(ph + lm), spl = sinf(ph + lm);
    float* G = &g[t * 8];
    G[0] = ch;        G[1] = 0.0f;       // h00 = g00 = cos(th/2)
    G[2] = cp * sh;   G[3] = sp * sh;    // h01 = g10 = e^{i ph} sin
    G[4] = -cl * sh;  G[5] = -sl * sh;   // h10 = g01 = -e^{i lm} sin
    G[6] = cpl * ch;  G[7] = spl * ch;   // h11 = e^{i(ph+lm)} cos
  }
  __syncthreads();

  for (int l = NL - 1; l >= 0; --l) {
    // ---- Reversed CNOT block (apply q=9 first ... q=0 last), composed:
    // v'[k] = v[sigma_9(sigma_8(...sigma_0(k)...))];
    // sigma_q: if bit(9-q) of k set, flip bit(9-((q+1)%10)).
    {
      int j0 = t, j1 = t + NTHREADS;
#pragma unroll
      for (int q = 0; q < NQ; ++q) {
        const int cb = 9 - q;
        const int tb = 9 - ((q + 1) % NQ);
        j0 ^= ((j0 >> cb) & 1) << tb;
        j1 ^= ((j1 >> cb) & 1) << tb;
      }
      const float a0r = sre[j0], a0i = sim[j0];
      const float a1r = sre[j1], a1i = sim[j1];
      __syncthreads();
      sre[t] = a0r;            sim[t] = a0i;
      sre[t + NTHREADS] = a1r; sim[t + NTHREADS] = a1i;
      __syncthreads();
    }
    // ---- Reversed U3 block: q = 9..0, transposed gates.
    for (int q = NQ - 1; q >= 0; --q) {
      const int b = 9 - q;  // bit position of qubit q
      const int i0 = ((t >> b) << (b + 1)) | (t & ((1 << b) - 1));
      const int i1 = i0 | (1 << b);
      const float* G = &g[(l * NQ + q) * 8];
      const float g0r = G[0], g0i = G[1], g1r = G[2], g1i = G[3];
      const float g2r = G[4], g2i = G[5], g3r = G[6], g3i = G[7];
      const float v0r = sre[i0], v0i = sim[i0];
      const float v1r = sre[i1], v1i = sim[i1];
      const float n0r = g0r * v0r - g0i * v0i + g1r * v1r - g1i * v1i;
      const float n0i = g0r * v0i + g0i * v0r + g1r * v1i + g1i * v1r;
      const float n1r = g2r * v0r - g2i * v0i + g3r * v1r - g3i * v1i;
      const float n1i = g2r * v0i + g2i * v0r + g3r * v1i + g3i * v1r;
      // Each thread owns its pair (i0,i1) exclusively.
      sre[i0] = n0r; sim[i0] = n0i;
      sre[i1] = n1r; sim[i1] = n1i;
      __syncthreads();
    }
  }

  // Store REAL PART only: out_size = nstates*NST float32s.
  const size_t base = (size_t)s * NST;
  if (base + t < (size_t)out_size)
    out[base + t] = sre[t];
  if (base + t + NTHREADS < (size_t)out_size)
    out[base + t + NTHREADS] = sre[t + NTHREADS];
}

extern "C" void kernel_launch(void* const* d_in, const int* in_sizes, int n_in,
                              void* d_out, int out_size, void* d_ws, size_t ws_size,
                              hipStream_t stream) {
  const float* x = (const float*)d_in[0];   // [128,16,32,32] f32
  const float* w = (const float*)d_in[1];   // [5,10,3] f32
  float* out = (float*)d_out;               // float32 (real part of complex64)
  const int nstates = in_sizes[0] / NST;    // 2048
  qc_apply<<<nstates, NTHREADS, 0, stream>>>(x, w, out, out_size);
}

// Round 4
// 93.339 us; speedup vs baseline: 1.2081x; 1.2081x over previous
//
#include <hip/hip_runtime.h>

// out[s,i] = Re( U x_s ), applied as reverse-order transposed gate sim on a
// per-state LDS statevector. Per layer (reverse): [composed CNOT perm sigma,
// folded into the first gate pass's read indices] then [5 fused 2-qubit U3
// passes]. U3s within a layer commute (distinct qubits), so pairing bits
// (8,9),(6,7),(4,5),(2,3),(0,1) is valid. Qubit q <-> bit (9-q).
// LDS is float2 (re,im) -> ds_*_b64; index swizzle k ^ (((k>>4)&3)<<2)
// breaks the (2,3)-pass bank conflicts. Gates are prebuilt into d_ws by a
// tiny kernel; per-pass gate reads are wave-uniform (s_load/L1) -> no LDS.

#define NQ 10
#define NL 5
#define NST 1024
#define NTH 256

// Composed reversed-CNOT permutation (temporal chain, q=0 step first) —
// identical to the verified round-3 loop. GF(2)-linear.
constexpr int csigma(int i) {
  for (int q = 0; q < NQ; ++q) {
    const int cb = 9 - q;
    const int tb = 9 - ((q + 1) % NQ);
    i ^= ((i >> cb) & 1) << tb;
  }
  return i;
}

__device__ __forceinline__ int swz(int k) { return k ^ (((k >> 4) & 3) << 2); }

__global__ void build_gates(const float* __restrict__ w, float* __restrict__ gw) {
  const int t = threadIdx.x;
  if (t < NL * NQ) {
    const float th = w[t * 3 + 0], ph = w[t * 3 + 1], lm = w[t * 3 + 2];
    const float ch = cosf(0.5f * th), sh = sinf(0.5f * th);
    const float cl = cosf(lm), sl = sinf(lm);
    const float cp = cosf(ph), sp = sinf(ph);
    const float cpl = cosf(ph + lm), spl = sinf(ph + lm);
    float* G = gw + t * 8;  // transposed U3: h01=g10, h10=g01
    G[0] = ch;       G[1] = 0.0f;
    G[2] = cp * sh;  G[3] = sp * sh;
    G[4] = -cl * sh; G[5] = -sl * sh;
    G[6] = cpl * ch; G[7] = spl * ch;
  }
}

// complex 2x2 butterfly: (a,b) <- H (a,b), H rows packed as float4 (r,i,r,i)
__device__ __forceinline__ void bfly(float2& a, float2& b,
                                     const float4 g0, const float4 g1) {
  const float nar = g0.x * a.x - g0.y * a.y + g0.z * b.x - g0.w * b.y;
  const float nai = g0.x * a.y + g0.y * a.x + g0.z * b.y + g0.w * b.x;
  const float nbr = g1.x * a.x - g1.y * a.y + g1.z * b.x - g1.w * b.y;
  const float nbi = g1.x * a.y + g1.y * a.x + g1.z * b.y + g1.w * b.x;
  a = make_float2(nar, nai);
  b = make_float2(nbr, nbi);
}

__global__ __launch_bounds__(NTH, 8) void qc_apply(
    const float* __restrict__ x, const float* __restrict__ gw,
    float* __restrict__ out, int out_size) {
  __shared__ float2 sc[NST];
  const int s = blockIdx.x, t = threadIdx.x;

  // init: 4 contiguous floats -> phys quad (swz keeps 4t..4t+3 contiguous
  // and 16B-aligned), stored as 2x float4 with zero imag.
  const float4 xv = ((const float4*)(x + (size_t)s * NST))[t];
  {
    const int p0 = swz(4 * t);
    float4* s4 = (float4*)sc;
    s4[p0 / 2]     = make_float4(xv.x, 0.f, xv.y, 0.f);
    s4[p0 / 2 + 1] = make_float4(xv.z, 0.f, xv.w, 0.f);
  }
  __syncthreads();

  constexpr int S1 = csigma(1 << 8);
  constexpr int S2 = csigma(1 << 9);

  for (int l = NL - 1; l >= 0; --l) {
    const float4* g = (const float4*)(gw + (size_t)l * NQ * 8);

    // ---- merged pass: sigma gather + gates on bits (8,9) = qubits (1,0).
    // Thread quad logical indices: t, t+256, t+512, t+768.
    {
      int sb = t;  // sigma(t), runtime chain (sigma linear: partners via ^S1/^S2)
#pragma unroll
      for (int q = 0; q < NQ; ++q) {
        const int cb = 9 - q, tb = 9 - ((q + 1) % NQ);
        sb ^= ((sb >> cb) & 1) << tb;
      }
      float2 v00 = sc[swz(sb)];
      float2 v01 = sc[swz(sb ^ S1)];
      float2 v10 = sc[swz(sb ^ S2)];
      float2 v11 = sc[swz(sb ^ S1 ^ S2)];
      const float4 h1a = g[2], h1b = g[3];  // q=1 (bit 8)
      const float4 h2a = g[0], h2b = g[1];  // q=0 (bit 9)
      bfly(v00, v01, h1a, h1b);
      bfly(v10, v11, h1a, h1b);
      bfly(v00, v10, h2a, h2b);
      bfly(v01, v11, h2a, h2b);
      __syncthreads();  // all gathers done before overwriting
      sc[swz(t)]       = v00;
      sc[swz(t + 256)] = v01;
      sc[swz(t + 512)] = v10;
      sc[swz(t + 768)] = v11;
      __syncthreads();
    }

    // ---- passes p=3..0: bits (2p, 2p+1) = qubits (9-2p, 8-2p).
    // Threads own disjoint quads within a pass -> 1 barrier per pass.
#pragma unroll
    for (int p = 3; p >= 0; --p) {
      const int b1 = 2 * p;
      const int m1 = 1 << b1;
      const int base = ((t >> b1) << (b1 + 2)) | (t & (m1 - 1));
      float2 v00 = sc[swz(base)];
      float2 v01 = sc[swz(base + m1)];
      float2 v10 = sc[swz(base + 2 * m1)];
      float2 v11 = sc[swz(base + 3 * m1)];
      const int q1 = 9 - b1;  // gate for bit b1; bit b1+1 uses q1-1
      const float4 h1a = g[2 * q1],     h1b = g[2 * q1 + 1];
      const float4 h2a = g[2 * q1 - 2], h2b = g[2 * q1 - 1];
      bfly(v00, v01, h1a, h1b);
      bfly(v10, v11, h1a, h1b);
      bfly(v00, v10, h2a, h2b);
      bfly(v01, v11, h2a, h2b);
      sc[swz(base)]          = v00;
      sc[swz(base + m1)]     = v01;
      sc[swz(base + 2 * m1)] = v10;
      sc[swz(base + 3 * m1)] = v11;
      __syncthreads();
    }
  }

  // store real parts, coalesced
  const size_t ob = (size_t)s * NST;
#pragma unroll
  for (int j = 0; j < 4; ++j) {
    const int k = t + j * NTH;
    if (ob + (size_t)k < (size_t)out_size) out[ob + k] = sc[swz(k)].x;
  }
}

extern "C" void kernel_launch(void* const* d_in, const int* in_sizes, int n_in,
                              void* d_out, int out_size, void* d_ws, size_t ws_size,
                              hipStream_t stream) {
  const float* x = (const float*)d_in[0];   // [128,16,32,32] f32
  const float* w = (const float*)d_in[1];   // [5,10,3] f32
  float* out = (float*)d_out;               // f32 (real part of complex64)
  float* gw = (float*)d_ws;                 // 50 gates x 8 floats = 1600 B
  const int nstates = in_sizes[0] / NST;    // 2048
  build_gates<<<1, 64, 0, stream>>>(w, gw);
  qc_apply<<<nstates, NTH, 0, stream>>>(x, gw, out, out_size);
}